// Round 14
// baseline (74.375 us; speedup 1.0000x reference)
//
#include <hip/hip_runtime.h>

#define OC 32
#define IC 16
#define HH 128
#define WW 128
#define NB 8
#define RP 130                          // padded rows: rp = r+1, r in [-1,128]
#define PLANE (RP * WW)                 // 16640 dwords per (n,j) plane
#define TRIG_DW (NB * IC * PLANE)       // 2,129,920 dwords
#define A_OFF TRIG_DW
#define A_DW (OC * 48)                  // A-table [oc][m], 1536 dwords
#define TOTAL_DW (TRIG_DW + A_DW)

typedef __attribute__((ext_vector_type(8))) __bf16 bf16x8;
typedef __attribute__((ext_vector_type(4))) float f32x4;

#define INV_2PI 0.15915494309189535f

__device__ inline unsigned int pack2bf(float lo, float hi) {
    union { __bf16 h[2]; unsigned int u; } p;
    p.h[0] = (__bf16)lo;
    p.h[1] = (__bf16)hi;
    return p.u;
}

// v_sin/v_cos take REVOLUTIONS, no HW range-reduction; fract() is an EXACT
// period reduction in rev units. (Verified numerics: round 13, absmax 0.0625.)
__device__ inline void hw_sincos(float rad, float* sn, float* cs) {
    float rev = rad * INV_2PI;
    float fr = rev - floorf(rev);
    *sn = __builtin_amdgcn_sinf(fr);
    *cs = __builtin_amdgcn_cosf(fr);
}

// Kernel 1: full-occupancy streaming precompute.
//   ws[(n*16+j)*PLANE + rp*128 + w] = pack(cos R, sin R), rp=r+1; pad rows=(1,0)
//   ws[A_OFF + oc*48 + m]           = pack(cos th/3, -sin th/3), m=3j+kk
__global__ void trig_kernel(const float* __restrict__ x,
                            const float* __restrict__ theta,
                            unsigned int* __restrict__ ws) {
    int idx = blockIdx.x * 256 + threadIdx.x;
    if (idx >= TOTAL_DW) return;

    if (idx < TRIG_DW) {
        int w = idx & (WW - 1);
        int rowidx = idx >> 7;
        int rp = rowidx % RP;
        int pj = rowidx / RP;          // n*16+j
        unsigned int pk;
        int r = rp - 1;
        if (r >= 0 && r < HH) {
            const float* row = x + ((size_t)pj * HH + r) * WW;
            float c0 = row[w];
            float cm = (w > 0)      ? row[w - 1] : 0.f;
            float cp = (w < WW - 1) ? row[w + 1] : 0.f;
            float s = cm + c0 + cp;
            float sn, cs;
            hw_sincos(s, &sn, &cs);
            pk = pack2bf(cs, sn);
        } else {
            pk = 0x00003F80u;          // (cos,sin) = (1,0): zero-window identity
        }
        ws[idx] = pk;
    } else {
        int q = idx - A_OFF;           // q = oc*48 + m
        int oc = q / 48;
        int m = q - oc * 48;
        int j = m / 3;
        int kk = m - 3 * j;
        float th = theta[(oc * j) * 3 + kk];
        float sn, cs;
        hw_sincos(th, &sn, &cs);
        const float inv3 = 1.0f / 3.0f;
        ws[idx] = pack2bf(cs * inv3, -sn * inv3);
    }
}

// Kernel 2: pure MFMA GEMM, no LDS / no barrier / no branches.
// D[oc][px] = A(32x96) x B(96x128); fragment m-index = Kt*16 + lk*4 + e.
// B[px][m] = trig[n][j][rp = h0+hrow+kk][w],  j=m/3, kk=m%3.
__global__ __launch_bounds__(256, 4) void gemm_kernel(
        const unsigned int* __restrict__ ws,
        float* __restrict__ out) {
    const int tx = threadIdx.x;
    const int ty = threadIdx.y;

    const int bid = blockIdx.x;
    const int wbase = (bid & 1) * 64;
    const int hp = (bid >> 1) & 63;
    const int n  = bid >> 7;
    const int h0 = hp * 2;

    const int l15 = tx & 15;
    const int lk  = tx >> 4;

    const unsigned int* At = ws + A_OFF;

    // ---- A fragments: 6x dwordx4, L2-hot (shared by all blocks) ----
    union U4 { unsigned int u[4]; bf16x8 h; };
    bf16x8 afr[3][2];
#pragma unroll
    for (int Kt = 0; Kt < 3; ++Kt)
#pragma unroll
        for (int Mt = 0; Mt < 2; ++Mt) {
            U4 a;
            const unsigned int* p = At + (l15 + 16 * Mt) * 48 + Kt * 16 + lk * 4;
#pragma unroll
            for (int e = 0; e < 4; ++e) a.u[e] = p[e];
            afr[Kt][Mt] = a.h;
        }

    // ---- B fragments: 24 dword gathers (64B-contiguous per l15 group) ----
    bf16x8 bfr[3][2];
#pragma unroll
    for (int Nt = 0; Nt < 2; ++Nt) {
        int px = ty * 32 + 16 * Nt + l15;
        int hrow = px >> 6;
        int w = wbase + (px & 63);
        const unsigned int* base = ws + (size_t)n * IC * PLANE + w;
#pragma unroll
        for (int Kt = 0; Kt < 3; ++Kt) {
            U4 b;
#pragma unroll
            for (int e = 0; e < 4; ++e) {
                int m = Kt * 16 + lk * 4 + e;
                int j = m / 3;
                int kk = m - 3 * j;
                int rp = h0 + hrow + kk;            // (h0-1+hrow+kk)+1, in [0,130)
                b.u[e] = base[(size_t)j * PLANE + rp * WW];
            }
            bfr[Kt][Nt] = b.h;
        }
    }

    // ---- 12 MFMA ----
    f32x4 acc[2][2];
#pragma unroll
    for (int a = 0; a < 2; ++a)
#pragma unroll
        for (int b = 0; b < 2; ++b) acc[a][b] = (f32x4){0.f, 0.f, 0.f, 0.f};

#pragma unroll
    for (int Kt = 0; Kt < 3; ++Kt)
#pragma unroll
        for (int Mt = 0; Mt < 2; ++Mt)
#pragma unroll
            for (int Nt = 0; Nt < 2; ++Nt)
                acc[Mt][Nt] = __builtin_amdgcn_mfma_f32_16x16x32_bf16(
                    afr[Kt][Mt], bfr[Kt][Nt], acc[Mt][Nt], 0, 0, 0);

    // ---- epilogue (1/3 folded into A) ----
#pragma unroll
    for (int Mt = 0; Mt < 2; ++Mt)
#pragma unroll
        for (int Nt = 0; Nt < 2; ++Nt)
#pragma unroll
            for (int e = 0; e < 4; ++e) {
                int oc = 16 * Mt + lk * 4 + e;
                int px = ty * 32 + 16 * Nt + l15;
                int hrow = px >> 6, wloc = px & 63;
                out[(((size_t)n * OC + oc) * HH + (h0 + hrow)) * WW + (wbase + wloc)]
                    = acc[Mt][Nt][e];
            }
}

extern "C" void kernel_launch(void* const* d_in, const int* in_sizes, int n_in,
                              void* d_out, int out_size, void* d_ws, size_t ws_size,
                              hipStream_t stream) {
    const float* x     = (const float*)d_in[0];
    const float* theta = (const float*)d_in[1];
    float* out = (float*)d_out;
    unsigned int* ws = (unsigned int*)d_ws;

    trig_kernel<<<(TOTAL_DW + 255) / 256, 256, 0, stream>>>(x, theta, ws);

    dim3 block(64, 4, 1);
    gemm_kernel<<<NB * (HH / 2) * 2, block, 0, stream>>>(ws, out);
}